// Round 8
// baseline (328.309 us; speedup 1.0000x reference)
//
#include <hip/hip_runtime.h>

// LSTM decoder: B=1024, S=256, H=128, O=7, T=512
// gates = h @ (W_ih+W_hh).T + (b_ih+b_hh); c'=sig(f)c+sig(i)tanh(g);
// h'=sig(o)tanh(c'); pred = h' @ W_out.T + b_out
//
// Round 8 = round 7 minus the per-step pred straggler: h kept in a 32-slot
// LDS ring; every 32 steps a uniform batched pred phase (8 waves x full-M
// 16-row tiles, A from ring, B=W_out frags from LDS) stores to global.
// Steady-state step: ds_read A -> 16 MFMA -> in-reg gate select -> trans
// chain -> 1 ds_write -> barrier, identical work on ALL waves.

#define HH   128
#define SSEQ 256
#define TT   512
#define OO   7
#define RB   4
#define HSTR 144          // ring row stride in shorts (288B = 8-bank skew)
#define RING 32
#define SLOT (RB * HSTR)  // shorts per ring slot

typedef __attribute__((ext_vector_type(8))) short short8;
typedef __attribute__((ext_vector_type(4))) float f32x4;

__device__ __forceinline__ unsigned short f2bf(float x) {
    union { float f; unsigned u; } v; v.f = x;
    return (unsigned short)((v.u + 0x7FFF + ((v.u >> 16) & 1)) >> 16); // RNE
}
__device__ __forceinline__ float sigmoidf_(float x) {
    return __builtin_amdgcn_rcpf(1.f + __expf(-x));
}
__device__ __forceinline__ float tanhf_(float x) {
    return 1.f - 2.f * __builtin_amdgcn_rcpf(__expf(2.f * x) + 1.f);
}

__global__ void __launch_bounds__(512, 2)
lstm_decoder_kernel(const float* __restrict__ ctx,
                    const float* __restrict__ Wih,
                    const float* __restrict__ Whh,
                    const float* __restrict__ bih,
                    const float* __restrict__ bhh,
                    const float* __restrict__ Wout,
                    const float* __restrict__ bout,
                    float* __restrict__ out) {
    // h ring: slot t&31 holds h_t (bf16), rows padded to HSTR
    __shared__ __align__(16) unsigned short h_ring[RING * SLOT];   // 36 KB
    // W_out B-fragments, lane-indexed (conflict-free): [kt][lane][8]
    __shared__ __align__(16) unsigned short wo_frag[4][64][8];     // 4 KB

    const int tid  = threadIdx.x;
    const int lane = tid & 63;
    const int wave = tid >> 6;
    const int rowBase = blockIdx.x * RB;

    const int lo  = lane & 15;
    const int hi  = lane >> 4;       // 0..3: this lane's batch row AND k-slice
    const int col = wave * 16 + lo;  // this lane's gate/h column (0..127)
    const int arw = lo & 3;          // A-tile real row (rows replicated to 16)

    // folded biases for this lane's column
    const float bi  = bih[col]          + bhh[col];
    const float bf_ = bih[HH + col]     + bhh[HH + col];
    const float bg  = bih[2 * HH + col] + bhh[2 * HH + col];
    const float bo  = bih[3 * HH + col] + bhh[3 * HH + col];
    const float bo_pred = (lo < OO) ? bout[lo] : 0.f;

    // W fragments (B-operand): wave w, gate g -> n = g*128 + w*16 + lo,
    // lane holds W[n][k0..k0+7], k0 = kt*32 + hi*8
    short8 wfrag[4][4];
#pragma unroll
    for (int g = 0; g < 4; ++g) {
        const int n = g * HH + wave * 16 + lo;
#pragma unroll
        for (int kt = 0; kt < 4; ++kt) {
            const int k0 = kt * 32 + hi * 8;
            const float* p1 = Wih + (size_t)n * HH + k0;
            const float* p2 = Whh + (size_t)n * HH + k0;
            short8 w;
#pragma unroll
            for (int j = 0; j < 8; ++j) w[j] = (short)f2bf(p1[j] + p2[j]);
            wfrag[g][kt] = w;
        }
    }

    // W_out B-fragments into LDS (wave 0): lane holds Wout[lo][kt*32+hi*8..+8]
    if (wave == 0) {
#pragma unroll
        for (int kt = 0; kt < 4; ++kt) {
            const int k0 = kt * 32 + hi * 8;
            short8 w;
#pragma unroll
            for (int j = 0; j < 8; ++j)
                w[j] = (lo < OO) ? (short)f2bf(Wout[(size_t)lo * HH + k0 + j]) : (short)0;
            *(short8*)&wo_frag[kt][lane][0] = w;
        }
    }

    // h0 = context_seq[:, S-1, :] -> ring slot 0
    {
        const float v = ctx[(size_t)(rowBase + hi) * SSEQ * HH + (size_t)(SSEQ - 1) * HH + col];
        h_ring[hi * HSTR + col] = f2bf(v);
    }
    float c_st = 0.f;   // cell state for (row hi, col)
    __syncthreads();

    for (int it = 0; it <= TT; ++it) {
        // ---- batched pred phase: every 32 steps, preds for s = it-32..it-1.
        // Ring holds h_{it-31}..h_{it}; pred[s] = h_{s+1} @ Wout.T + b.
        // M-tile per wave: rows rho = 16*wave + (0..15), rho = slot*4 + brow.
        if (it >= 32 && (it & 31) == 0) {
            f32x4 accp = {0.f, 0.f, 0.f, 0.f};
            const int abase = (4 * wave + (lo >> 2)) * SLOT + (lo & 3) * HSTR + hi * 8;
#pragma unroll
            for (int kt = 0; kt < 4; ++kt) {
                const short8 a  = *(const short8*)&h_ring[abase + kt * 32];
                const short8 wp = *(const short8*)&wo_frag[kt][lane][0];
                accp = __builtin_amdgcn_mfma_f32_16x16x32_bf16(a, wp, accp, 0, 0, 0);
            }
            // C: col=lo, row(within tile)=4*hi+r -> slot sig=4*wave+hi, batch row r
            if (lo < OO) {
                const int sig = 4 * wave + hi;
                const int s   = sig ? (it - 33 + sig) : (it - 1);
#pragma unroll
                for (int r = 0; r < 4; ++r)
                    out[(size_t)(rowBase + r) * TT * OO + (size_t)s * OO + lo] =
                        accp[r] + bo_pred;
            }
            __syncthreads();   // pred reads done before slots get overwritten
        }

        if (it == TT) break;

        // ---- LSTM step: h_it (slot it&31) -> h_{it+1} (slot (it+1)&31) ----
        const int abase = (it & 31) * SLOT + arw * HSTR + hi * 8;
        short8 afrag[4];
#pragma unroll
        for (int kt = 0; kt < 4; ++kt)
            afrag[kt] = *(const short8*)&h_ring[abase + kt * 32];

        f32x4 acc0 = {0.f, 0.f, 0.f, 0.f};
        f32x4 acc1 = {0.f, 0.f, 0.f, 0.f};
        f32x4 acc2 = {0.f, 0.f, 0.f, 0.f};
        f32x4 acc3 = {0.f, 0.f, 0.f, 0.f};
#pragma unroll
        for (int kt = 0; kt < 4; ++kt) {
            acc0 = __builtin_amdgcn_mfma_f32_16x16x32_bf16(afrag[kt], wfrag[0][kt], acc0, 0, 0, 0);
            acc1 = __builtin_amdgcn_mfma_f32_16x16x32_bf16(afrag[kt], wfrag[1][kt], acc1, 0, 0, 0);
            acc2 = __builtin_amdgcn_mfma_f32_16x16x32_bf16(afrag[kt], wfrag[2][kt], acc2, 0, 0, 0);
            acc3 = __builtin_amdgcn_mfma_f32_16x16x32_bf16(afrag[kt], wfrag[3][kt], acc3, 0, 0, 0);
        }

        // C row = 4*hi + reg; A row m holds real row m&3 -> reg r at ANY hi is
        // the gate for real row r. Select reg r = hi in-register (no LDS).
        const bool m1 = (hi == 1), m2 = (hi == 2), m3 = (hi == 3);
        const float gi = m3 ? acc0[3] : m2 ? acc0[2] : m1 ? acc0[1] : acc0[0];
        const float gf = m3 ? acc1[3] : m2 ? acc1[2] : m1 ? acc1[1] : acc1[0];
        const float gg = m3 ? acc2[3] : m2 ? acc2[2] : m1 ? acc2[1] : acc2[0];
        const float go = m3 ? acc3[3] : m2 ? acc3[2] : m1 ? acc3[1] : acc3[0];

        const float si_ = sigmoidf_(gi + bi);
        const float sf_ = sigmoidf_(gf + bf_);
        const float so_ = sigmoidf_(go + bo);
        const float tg  = tanhf_(gg + bg);
        c_st = sf_ * c_st + si_ * tg;
        const float hnew = so_ * tanhf_(c_st);

        h_ring[((it + 1) & 31) * SLOT + hi * HSTR + col] = f2bf(hnew);
        __syncthreads();
    }
}

extern "C" void kernel_launch(void* const* d_in, const int* in_sizes, int n_in,
                              void* d_out, int out_size, void* d_ws, size_t ws_size,
                              hipStream_t stream) {
    const float* ctx  = (const float*)d_in[0];
    const float* Wih  = (const float*)d_in[1];
    const float* Whh  = (const float*)d_in[2];
    const float* bih  = (const float*)d_in[3];
    const float* bhh  = (const float*)d_in[4];
    const float* Wout = (const float*)d_in[5];
    const float* bout = (const float*)d_in[6];
    float* out = (float*)d_out;

    lstm_decoder_kernel<<<dim3(1024 / RB), dim3(512), 0, stream>>>(
        ctx, Wih, Whh, bih, bhh, Wout, bout, out);
}